// Round 1
// baseline (882.268 us; speedup 1.0000x reference)
//
#include <hip/hip_runtime.h>
#include <stdint.h>
#include <math.h>

typedef __attribute__((ext_vector_type(8))) short short8;
typedef __attribute__((ext_vector_type(4))) float floatx4;

#define B_DIM 2048
#define O_DIM 512
#define H_DIM 1024
#define P_DIM 1024
#define C_DIM 512
#define K_BIG 2560   // H + P + C
#define TAU 0.25f
#define OMT 0.75f

__device__ inline short f2bf(float f) {
  uint32_t u = __float_as_uint(f);
  u += 0x7FFFu + ((u >> 16) & 1u);   // round-to-nearest-even
  return (short)(u >> 16);
}

__device__ inline float sigmoidf_(float x) {
  return 1.0f / (1.0f + __expf(-x));
}

__device__ inline void async_copy16(const void* g, void* l) {
  __builtin_amdgcn_global_load_lds((__attribute__((address_space(1))) void*)g,
                                   (__attribute__((address_space(3))) void*)l,
                                   16, 0, 0);
}

// 128x128 output tile GEMM core. A: row-major, leading dim lda, pre-offset to tile row m0.
// BT: row-major N-major (i.e. B transposed), leading dim ldb, pre-offset to tile row n0.
// Wave w=tid>>6 in 2x2 grid computes 64x64 via 4x4 mfma_f32_16x16x32_bf16 frags.
__device__ inline void gemm_core(const short* __restrict__ A, int lda,
                                 const short* __restrict__ BT, int ldb,
                                 int K, short* ldsA, short* ldsB,
                                 floatx4 acc[4][4]) {
  const int tid = threadIdx.x;
  const int lane = tid & 63;
  const int w = tid >> 6;
  const int wm = w >> 1, wn = w & 1;
  const int fr = (lane >> 4) * 8;   // k offset within frag
  const int fm = lane & 15;         // row within frag

  for (int k0 = 0; k0 < K; k0 += 32) {
    // Stage A tile (128x32 bf16 = 8KB) and B tile (8KB); 512 16B-chunks each, 256 threads.
#pragma unroll
    for (int c2 = 0; c2 < 2; ++c2) {
      int chunk = c2 * 256 + tid;
      int row = chunk >> 2;
      int cc = (chunk & 3) * 8;
      async_copy16(A + row * lda + k0 + cc, ldsA + chunk * 8);
      async_copy16(BT + row * ldb + k0 + cc, ldsB + chunk * 8);
    }
    __builtin_amdgcn_s_waitcnt(0);
    __syncthreads();

    short8 afr[4], bfr[4];
#pragma unroll
    for (int i = 0; i < 4; ++i)
      afr[i] = *(const short8*)&ldsA[(wm * 64 + i * 16 + fm) * 32 + fr];
#pragma unroll
    for (int j = 0; j < 4; ++j)
      bfr[j] = *(const short8*)&ldsB[(wn * 64 + j * 16 + fm) * 32 + fr];
#pragma unroll
    for (int i = 0; i < 4; ++i)
#pragma unroll
      for (int j = 0; j < 4; ++j)
        acc[i][j] = __builtin_amdgcn_mfma_f32_16x16x32_bf16(afr[i], bfr[j], acc[i][j], 0, 0, 0);
    __syncthreads();
  }
}

// ---------------- setup kernels ----------------

// W_bigT [1024 n][2560 k] bf16 = [w_hp ; w_pp(zero diag) ; w_cp]^T
__global__ void k_build_wb(const float* __restrict__ w_hp, const float* __restrict__ w_pp,
                           const float* __restrict__ w_cp, short* __restrict__ WbT) {
  int idx = blockIdx.x * 256 + threadIdx.x;       // 1024*2560
  int n = idx / K_BIG, k = idx - n * K_BIG;
  float v;
  if (k < 1024) v = w_hp[k * P_DIM + n];
  else if (k < 2048) { int r = k - 1024; v = (r == n) ? 0.f : w_pp[r * P_DIM + n]; }
  else v = w_cp[(k - 2048) * P_DIM + n];
  WbT[idx] = f2bf(v);
}

// w_pcT [512 n][1024 k]
__global__ void k_build_pc(const float* __restrict__ w_pc, short* __restrict__ WpcT) {
  int idx = blockIdx.x * 256 + threadIdx.x;       // 512*1024
  int n = idx >> 10, k = idx & 1023;
  WpcT[idx] = f2bf(w_pc[k * C_DIM + n]);
}

// w_ohT [1024 n][512 k]
__global__ void k_build_woh(const float* __restrict__ w_oh, short* __restrict__ WohT) {
  int idx = blockIdx.x * 256 + threadIdx.x;       // 1024*512
  int n = idx >> 9, k = idx & 511;
  WohT[idx] = f2bf(w_oh[k * H_DIM + n]);
}

__global__ void k_build_in(const float* __restrict__ inp, short* __restrict__ inb) {
  int idx = blockIdx.x * 256 + threadIdx.x;       // 2048*512
  inb[idx] = f2bf(inp[idx]);
}

// X0 = 0.5 everywhere (ah0=ap0=ac0=0.5), p=0, c=0
__global__ void k_init(uint32_t* __restrict__ X0, float* __restrict__ p, float* __restrict__ c) {
  int i = blockIdx.x * 256 + threadIdx.x;         // grid sized for X0 words
  X0[i] = 0x3F003F00u;                            // two bf16 0.5
  if (i < B_DIM * P_DIM) p[i] = 0.f;
  if (i < B_DIM * C_DIM) c[i] = 0.f;
}

// oh = inputs @ w_oh + bias_h   (M=2048,N=1024,K=512) grid 16x8=128
__global__ __launch_bounds__(256) void k_gemm_oh(const short* __restrict__ inb,
                                                 const short* __restrict__ wohT,
                                                 const float* __restrict__ bias_h,
                                                 float* __restrict__ oh) {
  __shared__ short ldsA[128 * 32];
  __shared__ short ldsB[128 * 32];
  floatx4 acc[4][4] = {};
  int m0 = (blockIdx.x & 15) * 128, n0 = (blockIdx.x >> 4) * 128;
  gemm_core(inb + m0 * O_DIM, O_DIM, wohT + n0 * O_DIM, O_DIM, O_DIM, ldsA, ldsB, acc);
  const int lane = threadIdx.x & 63;
  const int w = threadIdx.x >> 6;
  const int wm = w >> 1, wn = w & 1;
#pragma unroll
  for (int i = 0; i < 4; ++i)
#pragma unroll
    for (int j = 0; j < 4; ++j)
#pragma unroll
      for (int r = 0; r < 4; ++r) {
        int m = m0 + wm * 64 + i * 16 + (lane >> 4) * 4 + r;
        int n = n0 + wn * 64 + j * 16 + (lane & 15);
        oh[m * H_DIM + n] = acc[i][j][r] + bias_h[n];
      }
}

// ---------------- per-timestep fused kernel ----------------
// blocks [0,128): p-GEMM  X(2048x2560) @ WbT -> p/ap update, writes out + Xn(ah,ap)
// blocks [128,192): c-GEMM ap(2048x1024) @ WpcT -> c/ac update, writes Xn(ac)
__global__ __launch_bounds__(256) void k_step(const short* __restrict__ Xc,
                                              short* __restrict__ Xn,
                                              const short* __restrict__ WbT,
                                              const short* __restrict__ WpcT,
                                              const float* __restrict__ bias_p,
                                              const float* __restrict__ bias_c,
                                              const float* __restrict__ oh,
                                              float* __restrict__ p,
                                              float* __restrict__ c,
                                              float* __restrict__ out_t,
                                              float ct) {
  __shared__ short ldsA[128 * 32];
  __shared__ short ldsB[128 * 32];
  floatx4 acc[4][4] = {};
  const int lane = threadIdx.x & 63;
  const int w = threadIdx.x >> 6;
  const int wm = w >> 1, wn = w & 1;
  const int bx = blockIdx.x;

  if (bx < 128) {
    int m0 = (bx & 15) * 128, n0 = (bx >> 4) * 128;
    gemm_core(Xc + m0 * K_BIG, K_BIG, WbT + n0 * K_BIG, K_BIG, K_BIG, ldsA, ldsB, acc);
#pragma unroll
    for (int i = 0; i < 4; ++i)
#pragma unroll
      for (int j = 0; j < 4; ++j)
#pragma unroll
        for (int r = 0; r < 4; ++r) {
          int m = m0 + wm * 64 + i * 16 + (lane >> 4) * 4 + r;
          int n = n0 + wn * 64 + j * 16 + (lane & 15);
          float pn = TAU * (acc[i][j][r] + bias_p[n]) + OMT * p[m * P_DIM + n];
          p[m * P_DIM + n] = pn;
          float ap = sigmoidf_(pn);
          out_t[m * P_DIM + n] = ap;
          Xn[m * K_BIG + H_DIM + n] = f2bf(ap);
          float ah = sigmoidf_(ct * oh[m * H_DIM + n]);
          Xn[m * K_BIG + n] = f2bf(ah);
        }
  } else {
    int b2 = bx - 128;
    int m0 = (b2 & 15) * 128, n0 = (b2 >> 4) * 128;
    gemm_core(Xc + m0 * K_BIG + H_DIM, K_BIG, WpcT + n0 * P_DIM, P_DIM, P_DIM, ldsA, ldsB, acc);
#pragma unroll
    for (int i = 0; i < 4; ++i)
#pragma unroll
      for (int j = 0; j < 4; ++j)
#pragma unroll
        for (int r = 0; r < 4; ++r) {
          int m = m0 + wm * 64 + i * 16 + (lane >> 4) * 4 + r;
          int n = n0 + wn * 64 + j * 16 + (lane & 15);
          float cn = TAU * (acc[i][j][r] + bias_c[n]) + OMT * c[m * C_DIM + n];
          c[m * C_DIM + n] = cn;
          Xn[m * K_BIG + H_DIM + P_DIM + n] = f2bf(sigmoidf_(cn));
        }
  }
}

extern "C" void kernel_launch(void* const* d_in, const int* in_sizes, int n_in,
                              void* d_out, int out_size, void* d_ws, size_t ws_size,
                              hipStream_t stream) {
  const float* inputs = (const float*)d_in[0];
  const float* w_oh   = (const float*)d_in[1];
  const float* w_hp   = (const float*)d_in[2];
  const float* w_pp   = (const float*)d_in[3];
  const float* w_pc   = (const float*)d_in[4];
  const float* w_cp   = (const float*)d_in[5];
  const float* bias_h = (const float*)d_in[6];
  const float* bias_p = (const float*)d_in[7];
  const float* bias_c = (const float*)d_in[8];
  float* out = (float*)d_out;

  char* ws = (char*)d_ws;
  auto alloc = [&](size_t bytes) {
    char* q = ws;
    ws += (bytes + 255) & ~(size_t)255;
    return q;
  };
  short*    WbT  = (short*)alloc((size_t)P_DIM * K_BIG * 2);      // 5 MB
  short*    WpcT = (short*)alloc((size_t)C_DIM * P_DIM * 2);      // 1 MB
  short*    WohT = (short*)alloc((size_t)H_DIM * O_DIM * 2);      // 1 MB
  short*    inb  = (short*)alloc((size_t)B_DIM * O_DIM * 2);      // 2 MB
  float*    oh   = (float*)alloc((size_t)B_DIM * H_DIM * 4);      // 8 MB
  short*    X0   = (short*)alloc((size_t)B_DIM * K_BIG * 2);      // 10.5 MB
  short*    X1   = (short*)alloc((size_t)B_DIM * K_BIG * 2);      // 10.5 MB
  float*    p    = (float*)alloc((size_t)B_DIM * P_DIM * 4);      // 8 MB
  float*    c    = (float*)alloc((size_t)B_DIM * C_DIM * 4);      // 4 MB

  // setup
  k_init<<<dim3((B_DIM * K_BIG / 2) / 256), 256, 0, stream>>>((uint32_t*)X0, p, c);
  k_build_wb<<<dim3((P_DIM * K_BIG) / 256), 256, 0, stream>>>(w_hp, w_pp, w_cp, WbT);
  k_build_pc<<<dim3((C_DIM * P_DIM) / 256), 256, 0, stream>>>(w_pc, WpcT);
  k_build_woh<<<dim3((H_DIM * O_DIM) / 256), 256, 0, stream>>>(w_oh, WohT);
  k_build_in<<<dim3((B_DIM * O_DIM) / 256), 256, 0, stream>>>(inputs, inb);
  k_gemm_oh<<<dim3(128), 256, 0, stream>>>(inb, WohT, bias_h, oh);

  // 12 recurrent steps
  short* Xbuf[2] = {X0, X1};
  for (int t = 1; t <= 12; ++t) {
    float ct = 1.0f - powf(OMT, (float)t);
    k_step<<<dim3(192), 256, 0, stream>>>(Xbuf[(t + 1) & 1], Xbuf[t & 1],
                                          WbT, WpcT, bias_p, bias_c, oh, p, c,
                                          out + (size_t)(t - 1) * B_DIM * P_DIM, ct);
  }
}

// Round 2
// 568.077 us; speedup vs baseline: 1.5531x; 1.5531x over previous
//
#include <hip/hip_runtime.h>
#include <stdint.h>
#include <math.h>

typedef __attribute__((ext_vector_type(8))) short short8;
typedef __attribute__((ext_vector_type(4))) float floatx4;

#define B_DIM 2048
#define O_DIM 512
#define H_DIM 1024
#define P_DIM 1024
#define C_DIM 512
#define K_BIG 2560   // H + P + C
#define TAU 0.25f
#define OMT 0.75f

// s_waitcnt imm: vmcnt(n) only; exp=7, lgkm=15 (don't wait)
#define VMCNT(n) ((n) | 0x0F70)

__device__ inline short f2bf(float f) {
  uint32_t u = __float_as_uint(f);
  u += 0x7FFFu + ((u >> 16) & 1u);   // round-to-nearest-even
  return (short)(u >> 16);
}

__device__ inline float sigmoidf_(float x) {
  return 1.0f / (1.0f + __expf(-x));
}

__device__ inline void async_copy16(const void* g, void* l) {
  __builtin_amdgcn_global_load_lds((__attribute__((address_space(1))) void*)g,
                                   (__attribute__((address_space(3))) void*)l,
                                   16, 0, 0);
}

// 64x64 output tile GEMM core, BK=32, double-buffered with in-flight prefetch.
// A: row-major [64 x K], lda; BT: row-major N-major [64 x K], ldb (both pre-offset
// to this block's tile). lds: 8192 shorts (16KB): buf b at lds + b*4096,
// A tile = first 2048 shorts, B tile = next 2048.
// Staging is column-chunk-swizzled (cc ^ (row>>1)&3) so frag reads are ~conflict-free.
// 4 waves in 2x2; each wave computes 32x32 via acc[2][2] mfma_f32_16x16x32_bf16.
__device__ inline void gemm_core64(const short* __restrict__ A, int lda,
                                   const short* __restrict__ BT, int ldb,
                                   int K, short* lds, floatx4 acc[2][2]) {
  const int tid = threadIdx.x;
  const int row = tid >> 2;                 // tile row 0..63
  const int ccs = tid & 3;                  // swizzled chunk slot
  const int cc  = ccs ^ ((row >> 1) & 3);   // logical column chunk fetched
  const short* gA = A + row * lda + cc * 8;
  const short* gB = BT + row * ldb + cc * 8;

  const int lane = tid & 63;
  const int fm = lane & 15, hi = lane >> 4;
  const int sw = (hi ^ ((fm >> 1) & 3)) * 8;          // swizzled k-chunk offset (shorts)
  const int w = tid >> 6, wm = w >> 1, wn = w & 1;
  const int aoff = (wm * 32 + fm) * 32 + sw;          // + i*16*32
  const int boff = 2048 + (wn * 32 + fm) * 32 + sw;   // + j*16*32

  // prefetch tile 0 into buf 0
  async_copy16(gA, lds + tid * 8);
  async_copy16(gB, lds + 2048 + tid * 8);

  const int nIter = K / 32;
  for (int it = 0; it < nIter; ++it) {
    const int cur = (it & 1) * 4096;
    const int nxt = cur ^ 4096;
    // barrier 1: all waves done reading `nxt` (from iter it-1) before new data lands
    __builtin_amdgcn_s_barrier();
    if (it + 1 < nIter) {
      async_copy16(gA + (it + 1) * 32, lds + nxt + tid * 8);
      async_copy16(gB + (it + 1) * 32, lds + nxt + 2048 + tid * 8);
      __builtin_amdgcn_s_waitcnt(VMCNT(2));   // tile `it` landed; prefetch still flying
    } else {
      __builtin_amdgcn_s_waitcnt(VMCNT(0));
    }
    // barrier 2: every wave's chunks for tile `it` are in LDS
    __builtin_amdgcn_s_barrier();

    short8 afr[2], bfr[2];
#pragma unroll
    for (int i = 0; i < 2; ++i)
      afr[i] = *(const short8*)&lds[cur + aoff + i * 16 * 32];
#pragma unroll
    for (int j = 0; j < 2; ++j)
      bfr[j] = *(const short8*)&lds[cur + boff + j * 16 * 32];
#pragma unroll
    for (int i = 0; i < 2; ++i)
#pragma unroll
      for (int j = 0; j < 2; ++j)
        acc[i][j] = __builtin_amdgcn_mfma_f32_16x16x32_bf16(afr[i], bfr[j], acc[i][j], 0, 0, 0);
  }
  // final barrier so epilogue LDS reuse (none) / next use is safe; also keeps
  // waves together before heavy global epilogue. Cheap.
  __builtin_amdgcn_s_barrier();
}

// ---------------- setup kernels ----------------

__global__ void k_build_wb(const float* __restrict__ w_hp, const float* __restrict__ w_pp,
                           const float* __restrict__ w_cp, short* __restrict__ WbT) {
  int idx = blockIdx.x * 256 + threadIdx.x;       // 1024*2560
  int n = idx / K_BIG, k = idx - n * K_BIG;
  float v;
  if (k < 1024) v = w_hp[k * P_DIM + n];
  else if (k < 2048) { int r = k - 1024; v = (r == n) ? 0.f : w_pp[r * P_DIM + n]; }
  else v = w_cp[(k - 2048) * P_DIM + n];
  WbT[idx] = f2bf(v);
}

__global__ void k_build_pc(const float* __restrict__ w_pc, short* __restrict__ WpcT) {
  int idx = blockIdx.x * 256 + threadIdx.x;       // 512*1024
  int n = idx >> 10, k = idx & 1023;
  WpcT[idx] = f2bf(w_pc[k * C_DIM + n]);
}

__global__ void k_build_woh(const float* __restrict__ w_oh, short* __restrict__ WohT) {
  int idx = blockIdx.x * 256 + threadIdx.x;       // 1024*512
  int n = idx >> 9, k = idx & 511;
  WohT[idx] = f2bf(w_oh[k * H_DIM + n]);
}

__global__ void k_build_in(const float* __restrict__ inp, short* __restrict__ inb) {
  int idx = blockIdx.x * 256 + threadIdx.x;       // 2048*512
  inb[idx] = f2bf(inp[idx]);
}

__global__ void k_init(uint32_t* __restrict__ X0, float* __restrict__ p, float* __restrict__ c) {
  int i = blockIdx.x * 256 + threadIdx.x;         // grid sized for X0 words
  X0[i] = 0x3F003F00u;                            // two bf16 0.5
  if (i < B_DIM * P_DIM) p[i] = 0.f;
  if (i < B_DIM * C_DIM) c[i] = 0.f;
}

// oh = inputs @ w_oh + bias_h   (M=2048,N=1024,K=512) grid 32x16=512
__global__ __launch_bounds__(256) void k_gemm_oh(const short* __restrict__ inb,
                                                 const short* __restrict__ wohT,
                                                 const float* __restrict__ bias_h,
                                                 float* __restrict__ oh) {
  __shared__ short lds[8192];
  floatx4 acc[2][2] = {};
  int m0 = (blockIdx.x & 31) * 64, n0 = (blockIdx.x >> 5) * 64;
  gemm_core64(inb + m0 * O_DIM, O_DIM, wohT + n0 * O_DIM, O_DIM, O_DIM, lds, acc);
  const int lane = threadIdx.x & 63;
  const int fm = lane & 15, hi = lane >> 4;
  const int w = threadIdx.x >> 6, wm = w >> 1, wn = w & 1;
#pragma unroll
  for (int i = 0; i < 2; ++i)
#pragma unroll
    for (int j = 0; j < 2; ++j)
#pragma unroll
      for (int r = 0; r < 4; ++r) {
        int m = m0 + wm * 32 + i * 16 + hi * 4 + r;
        int n = n0 + wn * 32 + j * 16 + fm;
        oh[m * H_DIM + n] = acc[i][j][r] + bias_h[n];
      }
}

// ---------------- per-timestep fused kernel ----------------
// blocks [0,512): p-GEMM  X(2048x2560) @ WbT -> p/ap update, writes out + Xn(ah,ap)
// blocks [512,768): c-GEMM ap(2048x1024) @ WpcT -> c/ac update, writes Xn(ac)
__global__ __launch_bounds__(256) void k_step(const short* __restrict__ Xc,
                                              short* __restrict__ Xn,
                                              const short* __restrict__ WbT,
                                              const short* __restrict__ WpcT,
                                              const float* __restrict__ bias_p,
                                              const float* __restrict__ bias_c,
                                              const float* __restrict__ oh,
                                              float* __restrict__ p,
                                              float* __restrict__ c,
                                              float* __restrict__ out_t,
                                              float ct) {
  __shared__ short lds[8192];
  floatx4 acc[2][2] = {};
  const int lane = threadIdx.x & 63;
  const int fm = lane & 15, hi = lane >> 4;
  const int w = threadIdx.x >> 6, wm = w >> 1, wn = w & 1;
  const int bx = blockIdx.x;

  if (bx < 512) {
    int m0 = (bx & 31) * 64, n0 = (bx >> 5) * 64;
    gemm_core64(Xc + m0 * K_BIG, K_BIG, WbT + n0 * K_BIG, K_BIG, K_BIG, lds, acc);
#pragma unroll
    for (int i = 0; i < 2; ++i)
#pragma unroll
      for (int j = 0; j < 2; ++j)
#pragma unroll
        for (int r = 0; r < 4; ++r) {
          int m = m0 + wm * 32 + i * 16 + hi * 4 + r;
          int n = n0 + wn * 32 + j * 16 + fm;
          float pn = TAU * (acc[i][j][r] + bias_p[n]) + OMT * p[m * P_DIM + n];
          p[m * P_DIM + n] = pn;
          float ap = sigmoidf_(pn);
          out_t[m * P_DIM + n] = ap;
          Xn[m * K_BIG + H_DIM + n] = f2bf(ap);
          float ah = sigmoidf_(ct * oh[m * H_DIM + n]);
          Xn[m * K_BIG + n] = f2bf(ah);
        }
  } else {
    int b2 = bx - 512;
    int m0 = (b2 & 31) * 64, n0 = (b2 >> 5) * 64;
    gemm_core64(Xc + m0 * K_BIG + H_DIM, K_BIG, WpcT + n0 * P_DIM, P_DIM, P_DIM, lds, acc);
#pragma unroll
    for (int i = 0; i < 2; ++i)
#pragma unroll
      for (int j = 0; j < 2; ++j)
#pragma unroll
        for (int r = 0; r < 4; ++r) {
          int m = m0 + wm * 32 + i * 16 + hi * 4 + r;
          int n = n0 + wn * 32 + j * 16 + fm;
          float cn = TAU * (acc[i][j][r] + bias_c[n]) + OMT * c[m * C_DIM + n];
          c[m * C_DIM + n] = cn;
          Xn[m * K_BIG + H_DIM + P_DIM + n] = f2bf(sigmoidf_(cn));
        }
  }
}

extern "C" void kernel_launch(void* const* d_in, const int* in_sizes, int n_in,
                              void* d_out, int out_size, void* d_ws, size_t ws_size,
                              hipStream_t stream) {
  const float* inputs = (const float*)d_in[0];
  const float* w_oh   = (const float*)d_in[1];
  const float* w_hp   = (const float*)d_in[2];
  const float* w_pp   = (const float*)d_in[3];
  const float* w_pc   = (const float*)d_in[4];
  const float* w_cp   = (const float*)d_in[5];
  const float* bias_h = (const float*)d_in[6];
  const float* bias_p = (const float*)d_in[7];
  const float* bias_c = (const float*)d_in[8];
  float* out = (float*)d_out;

  char* ws = (char*)d_ws;
  auto alloc = [&](size_t bytes) {
    char* q = ws;
    ws += (bytes + 255) & ~(size_t)255;
    return q;
  };
  short*    WbT  = (short*)alloc((size_t)P_DIM * K_BIG * 2);      // 5 MB
  short*    WpcT = (short*)alloc((size_t)C_DIM * P_DIM * 2);      // 1 MB
  short*    WohT = (short*)alloc((size_t)H_DIM * O_DIM * 2);      // 1 MB
  short*    inb  = (short*)alloc((size_t)B_DIM * O_DIM * 2);      // 2 MB
  float*    oh   = (float*)alloc((size_t)B_DIM * H_DIM * 4);      // 8 MB
  short*    X0   = (short*)alloc((size_t)B_DIM * K_BIG * 2);      // 10.5 MB
  short*    X1   = (short*)alloc((size_t)B_DIM * K_BIG * 2);      // 10.5 MB
  float*    p    = (float*)alloc((size_t)B_DIM * P_DIM * 4);      // 8 MB
  float*    c    = (float*)alloc((size_t)B_DIM * C_DIM * 4);      // 4 MB

  // setup
  k_init<<<dim3((B_DIM * K_BIG / 2) / 256), 256, 0, stream>>>((uint32_t*)X0, p, c);
  k_build_wb<<<dim3((P_DIM * K_BIG) / 256), 256, 0, stream>>>(w_hp, w_pp, w_cp, WbT);
  k_build_pc<<<dim3((C_DIM * P_DIM) / 256), 256, 0, stream>>>(w_pc, WpcT);
  k_build_woh<<<dim3((H_DIM * O_DIM) / 256), 256, 0, stream>>>(w_oh, WohT);
  k_build_in<<<dim3((B_DIM * O_DIM) / 256), 256, 0, stream>>>(inputs, inb);
  k_gemm_oh<<<dim3(512), 256, 0, stream>>>(inb, WohT, bias_h, oh);

  // 12 recurrent steps
  short* Xbuf[2] = {X0, X1};
  for (int t = 1; t <= 12; ++t) {
    float ct = 1.0f - powf(OMT, (float)t);
    k_step<<<dim3(768), 256, 0, stream>>>(Xbuf[(t + 1) & 1], Xbuf[t & 1],
                                          WbT, WpcT, bias_p, bias_c, oh, p, c,
                                          out + (size_t)(t - 1) * B_DIM * P_DIM, ct);
  }
}